// Round 1
// baseline (11501.423 us; speedup 1.0000x reference)
//
#include <hip/hip_runtime.h>
#include <math.h>

#define BATCHN   128
#define SEQN     64
#define WDIM     300
#define MDIM     512
#define HIDN     256
#define NGATES   1280   // 5*HIDN
#define MLPD     1024
#define NCLS     3

__device__ __forceinline__ float sigmoidf_(float x) {
    return 1.0f / (1.0f + __expf(-x));
}
__device__ __forceinline__ float tanhf_(float x) {
    x = fminf(fmaxf(x, -15.0f), 15.0f);
    float e = __expf(2.0f * x);
    return (e - 1.0f) / (e + 1.0f);
}

// ---------------------------------------------------------------------------
// K1: states[b,s,:] = embed_table[sentences[b,s]] @ W_proj + b_proj
// one block = 8 tokens; 256 threads; each thread computes cols {tid, tid+256}
// ---------------------------------------------------------------------------
__global__ __launch_bounds__(256)
void embed_proj_kernel(const int* __restrict__ sent,
                       const float* __restrict__ emb,
                       const float* __restrict__ Wp,
                       const float* __restrict__ bp,
                       float* __restrict__ out)
{
    __shared__ __align__(16) float se[8][304];
    const int tid  = threadIdx.x;
    const int row0 = blockIdx.x * 8;

    for (int idx = tid; idx < 8 * WDIM; idx += 256) {
        int r = idx / WDIM;
        int k = idx - r * WDIM;
        se[r][k] = emb[sent[row0 + r] * WDIM + k];
    }
    __syncthreads();

    float acc0[8], acc1[8];
#pragma unroll
    for (int r = 0; r < 8; ++r) { acc0[r] = 0.f; acc1[r] = 0.f; }

    for (int k = 0; k < WDIM; ++k) {
        float w0 = Wp[k * MDIM + tid];
        float w1 = Wp[k * MDIM + 256 + tid];
#pragma unroll
        for (int r = 0; r < 8; ++r) {
            float a = se[r][k];
            acc0[r] += a * w0;
            acc1[r] += a * w1;
        }
    }
    float b0 = bp[tid], b1 = bp[256 + tid];
#pragma unroll
    for (int r = 0; r < 8; ++r) {
        out[(row0 + r) * MDIM + tid]        = acc0[r] + b0;
        out[(row0 + r) * MDIM + 256 + tid]  = acc1[r] + b1;
    }
}

// ---------------------------------------------------------------------------
// K2: one tree-LSTM level, fused GEMM + gates.
// A row m (m = b*R + pos): concat( h(in[b,pos]), h(in[b,pos+1]) ), K=512
// B = [W_l ; W_r]  (512 x 1280)
// Block: 64 rows x (5 gates x 64-wide hid slice). 256 threads (tx16 x ty16),
// each thread: 4 rows x 5 gates x 4 cols = 80 accumulators -> full LSTM cell
// elementwise done in registers.
// grid = (ceil(M/64), 4 hid slices)
// ---------------------------------------------------------------------------
__global__ __launch_bounds__(256)
void tree_level_kernel(const float* __restrict__ in, float* __restrict__ out,
                       const float* __restrict__ Wl, const float* __restrict__ Wr,
                       const float* __restrict__ bcomp, int R)
{
    const int M     = BATCHN * R;
    const int m0    = blockIdx.x * 64;
    const int slice = blockIdx.y;          // 0..3 -> hid cols slice*64..+63
    const int tid   = threadIdx.x;
    const int tx    = tid & 15;
    const int ty    = tid >> 4;

    __shared__ __align__(16) float As[32][68];    // [k][m], padded
    __shared__ __align__(16) float Bs[32][324];   // [k][5*64], padded

    // A-loader row mapping (8 rows per thread, fixed across k-tiles)
    int lrow[8];   // global state row of the LEFT element, or -1 if invalid
    const int mlb = tid >> 5;
#pragma unroll
    for (int i = 0; i < 8; ++i) {
        int m = m0 + mlb + 8 * i;
        if (m < M) {
            int b = m / R;
            int pos = m - b * R;
            lrow[i] = b * SEQN + pos;
        } else lrow[i] = -1;
    }
    const int kk_l = tid & 31;

    float acc[4][5][4];
#pragma unroll
    for (int r = 0; r < 4; ++r)
#pragma unroll
        for (int g = 0; g < 5; ++g)
#pragma unroll
            for (int c = 0; c < 4; ++c) acc[r][g][c] = 0.f;

    for (int kt = 0; kt < 16; ++kt) {
        const float* __restrict__ Wsrc =
            (kt < 8) ? (Wl + kt * 32 * NGATES) : (Wr + (kt - 8) * 32 * NGATES);

        // ---- A tile (64 x 32), store k-major
        const int kg   = kt * 32 + kk_l;                 // 0..511
        const int radd = (kg >= HIDN) ? 1 : 0;           // right sibling?
        const int kloc = (kg >= HIDN) ? (kg - HIDN) : kg;
#pragma unroll
        for (int i = 0; i < 8; ++i) {
            float v = 0.f;
            if (lrow[i] >= 0)
                v = in[(lrow[i] + radd) * MDIM + kloc];
            As[kk_l][mlb + 8 * i] = v;
        }
        // ---- B tile (32 x 320): cols {gate*256 + slice*64 + jj}
#pragma unroll 8
        for (int i = 0; i < 40; ++i) {
            int idx = tid + i * 256;
            int kk  = idx / 320;
            int j   = idx - kk * 320;
            int gi  = j >> 6;
            int jj  = j & 63;
            Bs[kk][j] = Wsrc[kk * NGATES + gi * HIDN + slice * 64 + jj];
        }
        __syncthreads();

#pragma unroll
        for (int kk = 0; kk < 32; ++kk) {
            float4 a  = *(const float4*)&As[kk][ty * 4];
            float4 b0 = *(const float4*)&Bs[kk][  0 + tx * 4];
            float4 b1 = *(const float4*)&Bs[kk][ 64 + tx * 4];
            float4 b2 = *(const float4*)&Bs[kk][128 + tx * 4];
            float4 b3 = *(const float4*)&Bs[kk][192 + tx * 4];
            float4 b4 = *(const float4*)&Bs[kk][256 + tx * 4];
            float av[4] = {a.x, a.y, a.z, a.w};
#pragma unroll
            for (int r = 0; r < 4; ++r) {
                acc[r][0][0] += av[r] * b0.x; acc[r][0][1] += av[r] * b0.y;
                acc[r][0][2] += av[r] * b0.z; acc[r][0][3] += av[r] * b0.w;
                acc[r][1][0] += av[r] * b1.x; acc[r][1][1] += av[r] * b1.y;
                acc[r][1][2] += av[r] * b1.z; acc[r][1][3] += av[r] * b1.w;
                acc[r][2][0] += av[r] * b2.x; acc[r][2][1] += av[r] * b2.y;
                acc[r][2][2] += av[r] * b2.z; acc[r][2][3] += av[r] * b2.w;
                acc[r][3][0] += av[r] * b3.x; acc[r][3][1] += av[r] * b3.y;
                acc[r][3][2] += av[r] * b3.z; acc[r][3][3] += av[r] * b3.w;
                acc[r][4][0] += av[r] * b4.x; acc[r][4][1] += av[r] * b4.y;
                acc[r][4][2] += av[r] * b4.z; acc[r][4][3] += av[r] * b4.w;
            }
        }
        __syncthreads();
    }

    // ---- epilogue: LSTM cell for this thread's 4 rows x 4 cols
    const int col = slice * 64 + tx * 4;
    float biasv[5][4];
#pragma unroll
    for (int gi = 0; gi < 5; ++gi) {
        float4 b = *(const float4*)&bcomp[gi * HIDN + col];
        biasv[gi][0] = b.x; biasv[gi][1] = b.y; biasv[gi][2] = b.z; biasv[gi][3] = b.w;
    }

#pragma unroll
    for (int r = 0; r < 4; ++r) {
        int m = m0 + ty * 4 + r;
        if (m >= M) continue;
        int b   = m / R;
        int pos = m - b * R;
        const float* rowl = in + (b * SEQN + pos) * MDIM;
        const float* rowr = rowl + MDIM;
        float4 cl4 = *(const float4*)&rowl[HIDN + col];
        float4 cr4 = *(const float4*)&rowr[HIDN + col];
        float clv[4] = {cl4.x, cl4.y, cl4.z, cl4.w};
        float crv[4] = {cr4.x, cr4.y, cr4.z, cr4.w};
        float hv[4], cv[4];
#pragma unroll
        for (int cc = 0; cc < 4; ++cc) {
            float i_ = acc[r][0][cc] + biasv[0][cc];
            float fl = acc[r][1][cc] + biasv[1][cc];
            float fr = acc[r][2][cc] + biasv[2][cc];
            float o_ = acc[r][3][cc] + biasv[3][cc];
            float g_ = acc[r][4][cc] + biasv[4][cc];
            float c  = clv[cc] * sigmoidf_(fl) + crv[cc] * sigmoidf_(fr)
                     + sigmoidf_(i_) * tanhf_(g_);
            hv[cc] = sigmoidf_(o_) * tanhf_(c);
            cv[cc] = c;
        }
        float* orow = out + (b * SEQN + pos) * MDIM;
        *(float4*)&orow[col]        = make_float4(hv[0], hv[1], hv[2], hv[3]);
        *(float4*)&orow[HIDN + col] = make_float4(cv[0], cv[1], cv[2], cv[3]);
    }
}

// ---------------------------------------------------------------------------
// K3: dense layer  out[M=128, N] = act(A[128, K] @ W[K, N] + bias)
// block: 8 rows x 256 cols; A rows staged in LDS.
// grid = (16, ceil(N/256))
// ---------------------------------------------------------------------------
template <int K, int N, bool RELU>
__global__ __launch_bounds__(256)
void mlp_kernel(const float* __restrict__ A, int lda,
                const float* __restrict__ W,
                const float* __restrict__ bias,
                float* __restrict__ out)
{
    __shared__ float Arow[8][K];
    const int tid = threadIdx.x;
    const int r0  = blockIdx.x * 8;

    for (int idx = tid; idx < 8 * K; idx += 256) {
        int r = idx / K;
        int k = idx & (K - 1);
        Arow[r][k] = A[(r0 + r) * lda + k];
    }
    __syncthreads();

    const int c = blockIdx.y * 256 + tid;
    if (c < N) {
        float acc[8];
#pragma unroll
        for (int r = 0; r < 8; ++r) acc[r] = 0.f;
        for (int k = 0; k < K; ++k) {
            float w = W[k * N + c];
#pragma unroll
            for (int r = 0; r < 8; ++r) acc[r] += Arow[r][k] * w;
        }
        float bv = bias[c];
#pragma unroll
        for (int r = 0; r < 8; ++r) {
            float v = acc[r] + bv;
            if (RELU) v = fmaxf(v, 0.f);
            out[(r0 + r) * N + c] = v;
        }
    }
}

// ---------------------------------------------------------------------------
extern "C" void kernel_launch(void* const* d_in, const int* in_sizes, int n_in,
                              void* d_out, int out_size, void* d_ws, size_t ws_size,
                              hipStream_t stream)
{
    const int*   sent = (const int*)d_in[0];
    // d_in[1] = transitions (unused by reference)
    const float* emb  = (const float*)d_in[2];
    const float* Wp   = (const float*)d_in[3];
    const float* bp   = (const float*)d_in[4];
    const float* Wl   = (const float*)d_in[5];
    const float* Wr   = (const float*)d_in[6];
    const float* bc   = (const float*)d_in[7];
    const float* W0   = (const float*)d_in[8];
    const float* b0   = (const float*)d_in[9];
    const float* W1   = (const float*)d_in[10];
    const float* b1   = (const float*)d_in[11];
    const float* Wo   = (const float*)d_in[12];
    const float* bo   = (const float*)d_in[13];
    float* outp = (float*)d_out;

    const size_t STATES = (size_t)BATCHN * SEQN * MDIM;   // 4.19M floats
    float* buf0 = (float*)d_ws;
    float* buf1 = buf0 + STATES;
    float* x0   = buf1 + STATES;
    float* x1   = x0 + (size_t)BATCHN * MLPD;

    // 1) embedding gather + projection
    embed_proj_kernel<<<(BATCHN * SEQN) / 8, 256, 0, stream>>>(sent, emb, Wp, bp, buf0);

    // 2) 63 sequential tree-LSTM levels (ping-pong buffers)
    float* cur = buf0;
    float* nxt = buf1;
    for (int R = SEQN - 1; R >= 1; --R) {
        int M = BATCHN * R;
        dim3 grid((M + 63) / 64, 4);
        tree_level_kernel<<<grid, 256, 0, stream>>>(cur, nxt, Wl, Wr, bc, R);
        float* t = cur; cur = nxt; nxt = t;
    }

    // 3) MLP head: h = states[:,0] (full 512-d state vector)
    mlp_kernel<512,  MLPD, true ><<<dim3(16, 4), 256, 0, stream>>>(cur, SEQN * MDIM, W0, b0, x0);
    mlp_kernel<MLPD, MLPD, true ><<<dim3(16, 4), 256, 0, stream>>>(x0, MLPD, W1, b1, x1);
    mlp_kernel<MLPD, NCLS, false><<<dim3(16, 1), 256, 0, stream>>>(x1, MLPD, Wo, bo, outp);
}

// Round 2
// 3398.969 us; speedup vs baseline: 3.3838x; 3.3838x over previous
//
#include <hip/hip_runtime.h>
#include <hip/hip_bf16.h>
#include <math.h>

#define BATCHN   128
#define SEQN     64
#define WDIM     300
#define MDIM     512
#define HIDN     256
#define NGATES   1280   // 5*HIDN
#define MLPD     1024
#define NCLS     3

typedef __bf16 bf16x8 __attribute__((ext_vector_type(8)));
typedef float  f32x4  __attribute__((ext_vector_type(4)));

__device__ __forceinline__ float sigmoidf_(float x) {
    return 1.0f / (1.0f + __expf(-x));
}
__device__ __forceinline__ float tanhf_(float x) {
    x = fminf(fmaxf(x, -15.0f), 15.0f);
    float e = __expf(2.0f * x);
    return (e - 1.0f) / (e + 1.0f);
}

// ---------------------------------------------------------------------------
// Pack B = [W_l ; W_r] (512 x 1280 fp32) into bf16 MFMA-fragment order:
// Bp[kc][n][j] with k = kc*8 + j  ->  lane's 8 k-elems are 16B contiguous.
// ---------------------------------------------------------------------------
__global__ __launch_bounds__(256)
void pack_B_kernel(const float* __restrict__ Wl, const float* __restrict__ Wr,
                   __hip_bfloat16* __restrict__ Bp)
{
    int idx = blockIdx.x * 256 + threadIdx.x;      // over [64][1280] (kc, n)
    if (idx >= 64 * NGATES) return;
    int kc = idx / NGATES;
    int n  = idx - kc * NGATES;
    __hip_bfloat16 tmp[8];
#pragma unroll
    for (int j = 0; j < 8; ++j) {
        int k = kc * 8 + j;
        float v = (k < HIDN) ? Wl[k * NGATES + n] : Wr[(k - HIDN) * NGATES + n];
        tmp[j] = __float2bfloat16(v);
    }
    // 16B contiguous store
    *(bf16x8*)(Bp + (size_t)idx * 8) = *(const bf16x8*)tmp;
}

// ---------------------------------------------------------------------------
// K1: states[b,s,:] = embed_table[sentences[b,s]] @ W_proj + b_proj
// h part (cols 0..255) -> bf16 hbuf; c part (cols 256..511) -> f32 cbuf
// ---------------------------------------------------------------------------
__global__ __launch_bounds__(256)
void embed_proj_kernel(const int* __restrict__ sent,
                       const float* __restrict__ emb,
                       const float* __restrict__ Wp,
                       const float* __restrict__ bp,
                       __hip_bfloat16* __restrict__ hout,
                       float* __restrict__ cout)
{
    __shared__ __align__(16) float se[8][304];
    const int tid  = threadIdx.x;
    const int row0 = blockIdx.x * 8;

    for (int idx = tid; idx < 8 * WDIM; idx += 256) {
        int r = idx / WDIM;
        int k = idx - r * WDIM;
        se[r][k] = emb[sent[row0 + r] * WDIM + k];
    }
    __syncthreads();

    float acc0[8], acc1[8];
#pragma unroll
    for (int r = 0; r < 8; ++r) { acc0[r] = 0.f; acc1[r] = 0.f; }

    for (int k = 0; k < WDIM; ++k) {
        float w0 = Wp[k * MDIM + tid];          // h col
        float w1 = Wp[k * MDIM + 256 + tid];    // c col
#pragma unroll
        for (int r = 0; r < 8; ++r) {
            float a = se[r][k];
            acc0[r] += a * w0;
            acc1[r] += a * w1;
        }
    }
    float b0 = bp[tid], b1 = bp[256 + tid];
#pragma unroll
    for (int r = 0; r < 8; ++r) {
        hout[(size_t)(row0 + r) * HIDN + tid] = __float2bfloat16(acc0[r] + b0);
        cout[(size_t)(row0 + r) * HIDN + tid] = acc1[r] + b1;
    }
}

// ---------------------------------------------------------------------------
// K2: one tree-LSTM level via MFMA. No LDS, no syncthreads.
// A[m, 0:512] = [h_l(m) | h_r(m)] (bf16), B = packed [Wl;Wr] (bf16).
// Block: 4 waves x 32 rows = 128 rows (exactly BATCH per position),
// grid = (R, 4 hid slices of 64 cols). Wave: 2 rowfrags x 4 colfrags x 5
// gates = 40 mfma_f32_16x16x32_bf16 chains; LSTM cell fused in registers.
// ---------------------------------------------------------------------------
__global__ __launch_bounds__(256)
void tree_level_mfma(const __hip_bfloat16* __restrict__ h_in,
                     const float* __restrict__ c_in,
                     __hip_bfloat16* __restrict__ h_out,
                     float* __restrict__ c_out,
                     const __hip_bfloat16* __restrict__ Bp,
                     const float* __restrict__ bc, int R)
{
    const int lane = threadIdx.x & 63;
    const int wid  = threadIdx.x >> 6;
    const int m0   = blockIdx.x * 128 + wid * 32;
    const int slice = blockIdx.y;                 // hid cols slice*64..+63
    const int l15  = lane & 15;
    const int kgrp = lane >> 4;

    // A-fragment source rows (fixed over k-steps): row = lane&15
    int srowA[2];
#pragma unroll
    for (int rf = 0; rf < 2; ++rf) {
        int m = m0 + rf * 16 + l15;
        int b = m / R;
        srowA[rf] = b * SEQN + (m - b * R);
    }

    f32x4 acc[2][4][5];
#pragma unroll
    for (int rf = 0; rf < 2; ++rf)
#pragma unroll
        for (int cf = 0; cf < 4; ++cf)
#pragma unroll
            for (int g = 0; g < 5; ++g)
                acc[rf][cf][g] = (f32x4){0.f, 0.f, 0.f, 0.f};

    const bf16x8* BpV = (const bf16x8*)Bp;

    for (int kt = 0; kt < 16; ++kt) {
        const int kg   = kt * 32 + kgrp * 8;      // global k for this lane
        const int half = kg >> 8;                 // 0 = h_l, 1 = h_r
        const int kl   = kg & 255;
        bf16x8 a0 = *(const bf16x8*)(h_in + (size_t)(srowA[0] + half) * HIDN + kl);
        bf16x8 a1 = *(const bf16x8*)(h_in + (size_t)(srowA[1] + half) * HIDN + kl);
        const bf16x8* Brow = BpV + (size_t)(kt * 4 + kgrp) * NGATES + slice * 64 + l15;
#pragma unroll
        for (int g = 0; g < 5; ++g)
#pragma unroll
            for (int cf = 0; cf < 4; ++cf) {
                bf16x8 bfr = Brow[g * HIDN + cf * 16];
                acc[0][cf][g] = __builtin_amdgcn_mfma_f32_16x16x32_bf16(a0, bfr, acc[0][cf][g], 0, 0, 0);
                acc[1][cf][g] = __builtin_amdgcn_mfma_f32_16x16x32_bf16(a1, bfr, acc[1][cf][g], 0, 0, 0);
            }
    }

    // ---- epilogue: C/D layout col = lane&15, row = (lane>>4)*4 + reg
    const int colbase = slice * 64 + l15;
    float bias[4][5];
#pragma unroll
    for (int cf = 0; cf < 4; ++cf)
#pragma unroll
        for (int g = 0; g < 5; ++g)
            bias[cf][g] = bc[g * HIDN + colbase + cf * 16];

#pragma unroll
    for (int rf = 0; rf < 2; ++rf)
#pragma unroll
        for (int reg = 0; reg < 4; ++reg) {
            int m = m0 + rf * 16 + kgrp * 4 + reg;
            int b = m / R;
            int srow = b * SEQN + (m - b * R);
            const float* cl = c_in + (size_t)srow * HIDN;
            const float* cr = cl + HIDN;
            __hip_bfloat16* ho = h_out + (size_t)srow * HIDN;
            float*          co = c_out + (size_t)srow * HIDN;
#pragma unroll
            for (int cf = 0; cf < 4; ++cf) {
                int col = colbase + cf * 16;
                float i_ = acc[rf][cf][0][reg] + bias[cf][0];
                float fl = acc[rf][cf][1][reg] + bias[cf][1];
                float fr = acc[rf][cf][2][reg] + bias[cf][2];
                float o_ = acc[rf][cf][3][reg] + bias[cf][3];
                float g_ = acc[rf][cf][4][reg] + bias[cf][4];
                float c  = cl[col] * sigmoidf_(fl) + cr[col] * sigmoidf_(fr)
                         + sigmoidf_(i_) * tanhf_(g_);
                ho[col] = __float2bfloat16(sigmoidf_(o_) * tanhf_(c));
                co[col] = c;
            }
        }
}

// ---------------------------------------------------------------------------
// Assemble MLP input: x[b, :] = [ h(root_b) (bf16->f32) | c(root_b) (f32) ]
// ---------------------------------------------------------------------------
__global__ __launch_bounds__(256)
void gather_root_kernel(const __hip_bfloat16* __restrict__ h,
                        const float* __restrict__ c,
                        float* __restrict__ x)
{
    int idx = blockIdx.x * 256 + threadIdx.x;     // 128*512
    int row = idx >> 9;
    int col = idx & 511;
    size_t srow = (size_t)row * SEQN;             // root = pos 0
    float v = (col < HIDN) ? __bfloat162float(h[srow * HIDN + col])
                           : c[srow * HIDN + (col - HIDN)];
    x[idx] = v;
}

// ---------------------------------------------------------------------------
// K3: dense layer  out[M=128, N] = act(A[128, K] @ W[K, N] + bias)
// ---------------------------------------------------------------------------
template <int K, int N, bool RELU>
__global__ __launch_bounds__(256)
void mlp_kernel(const float* __restrict__ A, int lda,
                const float* __restrict__ W,
                const float* __restrict__ bias,
                float* __restrict__ out)
{
    __shared__ float Arow[8][K];
    const int tid = threadIdx.x;
    const int r0  = blockIdx.x * 8;

    for (int idx = tid; idx < 8 * K; idx += 256) {
        int r = idx / K;
        int k = idx & (K - 1);
        Arow[r][k] = A[(r0 + r) * lda + k];
    }
    __syncthreads();

    const int c = blockIdx.y * 256 + tid;
    if (c < N) {
        float acc[8];
#pragma unroll
        for (int r = 0; r < 8; ++r) acc[r] = 0.f;
        for (int k = 0; k < K; ++k) {
            float w = W[k * N + c];
#pragma unroll
            for (int r = 0; r < 8; ++r) acc[r] += Arow[r][k] * w;
        }
        float bv = bias[c];
#pragma unroll
        for (int r = 0; r < 8; ++r) {
            float v = acc[r] + bv;
            if (RELU) v = fmaxf(v, 0.f);
            out[(r0 + r) * N + c] = v;
        }
    }
}

// ---------------------------------------------------------------------------
extern "C" void kernel_launch(void* const* d_in, const int* in_sizes, int n_in,
                              void* d_out, int out_size, void* d_ws, size_t ws_size,
                              hipStream_t stream)
{
    const int*   sent = (const int*)d_in[0];
    // d_in[1] = transitions (unused by reference)
    const float* emb  = (const float*)d_in[2];
    const float* Wp   = (const float*)d_in[3];
    const float* bp   = (const float*)d_in[4];
    const float* Wl   = (const float*)d_in[5];
    const float* Wr   = (const float*)d_in[6];
    const float* bc   = (const float*)d_in[7];
    const float* W0   = (const float*)d_in[8];
    const float* b0   = (const float*)d_in[9];
    const float* W1   = (const float*)d_in[10];
    const float* b1   = (const float*)d_in[11];
    const float* Wo   = (const float*)d_in[12];
    const float* bo   = (const float*)d_in[13];
    float* outp = (float*)d_out;

    const size_t NSTATE = (size_t)BATCHN * SEQN * HIDN;   // 2.097M elems

    char* p = (char*)d_ws;
    __hip_bfloat16* h0 = (__hip_bfloat16*)p;  p += NSTATE * 2;
    __hip_bfloat16* h1 = (__hip_bfloat16*)p;  p += NSTATE * 2;
    float* c0 = (float*)p;                    p += NSTATE * 4;
    float* c1 = (float*)p;                    p += NSTATE * 4;
    __hip_bfloat16* Bp = (__hip_bfloat16*)p;  p += (size_t)512 * NGATES * 2;
    float* xr = (float*)p;                    p += (size_t)BATCHN * MDIM * 4;
    float* x0 = (float*)p;                    p += (size_t)BATCHN * MLPD * 4;
    float* x1 = (float*)p;                    p += (size_t)BATCHN * MLPD * 4;

    // 0) pack weights to bf16 fragment layout (same work every call)
    pack_B_kernel<<<(64 * NGATES + 255) / 256, 256, 0, stream>>>(Wl, Wr, Bp);

    // 1) embedding gather + projection
    embed_proj_kernel<<<(BATCHN * SEQN) / 8, 256, 0, stream>>>(sent, emb, Wp, bp, h0, c0);

    // 2) 63 sequential tree-LSTM levels (ping-pong h/c buffers)
    __hip_bfloat16* hc = h0; __hip_bfloat16* hn = h1;
    float* cc = c0; float* cn = c1;
    for (int R = SEQN - 1; R >= 1; --R) {
        dim3 grid(R, 4);
        tree_level_mfma<<<grid, 256, 0, stream>>>(hc, cc, hn, cn, Bp, bc, R);
        __hip_bfloat16* th = hc; hc = hn; hn = th;
        float* tc = cc; cc = cn; cn = tc;
    }

    // 3) MLP head on root states
    gather_root_kernel<<<(BATCHN * MDIM) / 256, 256, 0, stream>>>(hc, cc, xr);
    mlp_kernel<512,  MLPD, true ><<<dim3(16, 4), 256, 0, stream>>>(xr, MDIM, W0, b0, x0);
    mlp_kernel<MLPD, MLPD, true ><<<dim3(16, 4), 256, 0, stream>>>(x0, MLPD, W1, b1, x1);
    mlp_kernel<MLPD, NCLS, false><<<dim3(16, 1), 256, 0, stream>>>(x1, MLPD, Wo, bo, outp);
}

// Round 3
// 2241.216 us; speedup vs baseline: 5.1318x; 1.5166x over previous
//
#include <hip/hip_runtime.h>
#include <hip/hip_bf16.h>
#include <math.h>

#define BATCHN   128
#define SEQN     64
#define WDIM     300
#define MDIM     512
#define HIDN     256
#define NGATES   1280   // 5*HIDN
#define MLPD     1024
#define NCLS     3

typedef __bf16 bf16x8 __attribute__((ext_vector_type(8)));
typedef float  f32x4  __attribute__((ext_vector_type(4)));

__device__ __forceinline__ float sigmoidf_(float x) {
    return 1.0f / (1.0f + __expf(-x));
}
__device__ __forceinline__ float tanhf_(float x) {
    x = fminf(fmaxf(x, -15.0f), 15.0f);
    float e = __expf(2.0f * x);
    return (e - 1.0f) / (e + 1.0f);
}

// ---------------------------------------------------------------------------
// Pack B = [W_l ; W_r] (512 x 1280 fp32) into bf16 MFMA-fragment order:
// Bp[kc][n][j] with k = kc*8 + j  ->  lane's 8 k-elems are 16B contiguous.
// ---------------------------------------------------------------------------
__global__ __launch_bounds__(256)
void pack_B_kernel(const float* __restrict__ Wl, const float* __restrict__ Wr,
                   __hip_bfloat16* __restrict__ Bp)
{
    int idx = blockIdx.x * 256 + threadIdx.x;      // over [64][1280] (kc, n)
    if (idx >= 64 * NGATES) return;
    int kc = idx / NGATES;
    int n  = idx - kc * NGATES;
    __hip_bfloat16 tmp[8];
#pragma unroll
    for (int j = 0; j < 8; ++j) {
        int k = kc * 8 + j;
        float v = (k < HIDN) ? Wl[k * NGATES + n] : Wr[(k - HIDN) * NGATES + n];
        tmp[j] = __float2bfloat16(v);
    }
    *(bf16x8*)(Bp + (size_t)idx * 8) = *(const bf16x8*)tmp;
}

// ---------------------------------------------------------------------------
// K1: states[b,s,:] = embed_table[sentences[b,s]] @ W_proj + b_proj
// h part (cols 0..255) -> bf16 hbuf; c part (cols 256..511) -> f32 cbuf
// ---------------------------------------------------------------------------
__global__ __launch_bounds__(256)
void embed_proj_kernel(const int* __restrict__ sent,
                       const float* __restrict__ emb,
                       const float* __restrict__ Wp,
                       const float* __restrict__ bp,
                       __hip_bfloat16* __restrict__ hout,
                       float* __restrict__ cout)
{
    __shared__ __align__(16) float se[8][304];
    const int tid  = threadIdx.x;
    const int row0 = blockIdx.x * 8;

    for (int idx = tid; idx < 8 * WDIM; idx += 256) {
        int r = idx / WDIM;
        int k = idx - r * WDIM;
        se[r][k] = emb[sent[row0 + r] * WDIM + k];
    }
    __syncthreads();

    float acc0[8], acc1[8];
#pragma unroll
    for (int r = 0; r < 8; ++r) { acc0[r] = 0.f; acc1[r] = 0.f; }

    for (int k = 0; k < WDIM; ++k) {
        float w0 = Wp[k * MDIM + tid];          // h col
        float w1 = Wp[k * MDIM + 256 + tid];    // c col
#pragma unroll
        for (int r = 0; r < 8; ++r) {
            float a = se[r][k];
            acc0[r] += a * w0;
            acc1[r] += a * w1;
        }
    }
    float b0 = bp[tid], b1 = bp[256 + tid];
#pragma unroll
    for (int r = 0; r < 8; ++r) {
        hout[(size_t)(row0 + r) * HIDN + tid] = __float2bfloat16(acc0[r] + b0);
        cout[(size_t)(row0 + r) * HIDN + tid] = acc1[r] + b1;
    }
}

// ---------------------------------------------------------------------------
// K2: one tree-LSTM level via MFMA, B staged through LDS (double-buffered).
// Block = 4 waves = all 128 batch rows at tree position p = blockIdx.x.
// grid = (R, 4 hid-col slices of 64). Wave: 32 rows x 64 hid cols x 5 gates.
// B slice staged in K-chunks of 32 via global_load_lds (20 x 1KB segments,
// wave w stages kc8 = w), shared by all 4 waves -> 4x less L2 traffic.
// ---------------------------------------------------------------------------
__global__ __launch_bounds__(256)
void tree_level_mfma(const __hip_bfloat16* __restrict__ h_in,
                     const float* __restrict__ c_in,
                     __hip_bfloat16* __restrict__ h_out,
                     float* __restrict__ c_out,
                     const __hip_bfloat16* __restrict__ Bp,
                     const float* __restrict__ bc)
{
    __shared__ __align__(16) __hip_bfloat16 Bs[2][4][320][8];   // 40 KB

    const int lane  = threadIdx.x & 63;
    const int wid   = threadIdx.x >> 6;
    const int p     = blockIdx.x;          // tree position (0..R-1)
    const int slice = blockIdx.y;          // hid cols slice*64..+63
    const int l15   = lane & 15;
    const int kgrp  = lane >> 4;
    const int b0    = wid * 32;            // this wave's batch-row base

    f32x4 acc[2][4][5];
#pragma unroll
    for (int rf = 0; rf < 2; ++rf)
#pragma unroll
        for (int cf = 0; cf < 4; ++cf)
#pragma unroll
            for (int g = 0; g < 5; ++g)
                acc[rf][cf][g] = (f32x4){0.f, 0.f, 0.f, 0.f};

    // stage K-chunk t into buffer buf: wave wid stages kc8 = wid, g = 0..4
#define STAGE_CHUNK(t, buf)                                                      \
    {                                                                            \
        const size_t kc_ = (size_t)(t) * 4 + wid;                                \
        _Pragma("unroll")                                                        \
        for (int g = 0; g < 5; ++g) {                                            \
            const __hip_bfloat16* src_ =                                         \
                Bp + (kc_ * NGATES + (size_t)g * HIDN + slice * 64 + lane) * 8;  \
            __builtin_amdgcn_global_load_lds(                                    \
                (const __attribute__((address_space(1))) unsigned int*)src_,     \
                (__attribute__((address_space(3))) unsigned int*)                \
                    &Bs[buf][wid][g * 64][0],                                    \
                16, 0, 0);                                                       \
        }                                                                        \
    }

    STAGE_CHUNK(0, 0);
    __syncthreads();

    for (int t = 0; t < 16; ++t) {
        const int buf = t & 1;
        if (t < 15) STAGE_CHUNK(t + 1, buf ^ 1);

        const int kg   = t * 32 + kgrp * 8;
        const int half = kg >> 8;                 // 0 = left child, 1 = right
        const int kl   = kg & 255;
        bf16x8 a0 = *(const bf16x8*)(h_in + ((size_t)(b0 + l15)      * SEQN + p + half) * HIDN + kl);
        bf16x8 a1 = *(const bf16x8*)(h_in + ((size_t)(b0 + 16 + l15) * SEQN + p + half) * HIDN + kl);

#pragma unroll
        for (int g = 0; g < 5; ++g)
#pragma unroll
            for (int cf = 0; cf < 4; ++cf) {
                bf16x8 bfr = *(const bf16x8*)&Bs[buf][kgrp][g * 64 + cf * 16 + l15][0];
                acc[0][cf][g] = __builtin_amdgcn_mfma_f32_16x16x32_bf16(a0, bfr, acc[0][cf][g], 0, 0, 0);
                acc[1][cf][g] = __builtin_amdgcn_mfma_f32_16x16x32_bf16(a1, bfr, acc[1][cf][g], 0, 0, 0);
            }
        __syncthreads();
    }
#undef STAGE_CHUNK

    // ---- epilogue: C/D layout col = lane&15, row = (lane>>4)*4 + reg
    const int colbase = slice * 64 + l15;
    float bias[4][5];
#pragma unroll
    for (int cf = 0; cf < 4; ++cf)
#pragma unroll
        for (int g = 0; g < 5; ++g)
            bias[cf][g] = bc[g * HIDN + colbase + cf * 16];

#pragma unroll
    for (int rf = 0; rf < 2; ++rf)
#pragma unroll
        for (int reg = 0; reg < 4; ++reg) {
            int srow = (b0 + rf * 16 + kgrp * 4 + reg) * SEQN + p;
            const float* cl = c_in + (size_t)srow * HIDN;
            const float* cr = cl + (size_t)HIDN;   // right child = srow + 1
            __hip_bfloat16* ho = h_out + (size_t)srow * HIDN;
            float*          co = c_out + (size_t)srow * HIDN;
#pragma unroll
            for (int cf = 0; cf < 4; ++cf) {
                int col = colbase + cf * 16;
                float i_ = acc[rf][cf][0][reg] + bias[cf][0];
                float fl = acc[rf][cf][1][reg] + bias[cf][1];
                float fr = acc[rf][cf][2][reg] + bias[cf][2];
                float o_ = acc[rf][cf][3][reg] + bias[cf][3];
                float g_ = acc[rf][cf][4][reg] + bias[cf][4];
                float c  = cl[col] * sigmoidf_(fl) + cr[col] * sigmoidf_(fr)
                         + sigmoidf_(i_) * tanhf_(g_);
                ho[col] = __float2bfloat16(sigmoidf_(o_) * tanhf_(c));
                co[col] = c;
            }
        }
}

// ---------------------------------------------------------------------------
// Assemble MLP input: x[b, :] = [ h(root_b) (bf16->f32) | c(root_b) (f32) ]
// ---------------------------------------------------------------------------
__global__ __launch_bounds__(256)
void gather_root_kernel(const __hip_bfloat16* __restrict__ h,
                        const float* __restrict__ c,
                        float* __restrict__ x)
{
    int idx = blockIdx.x * 256 + threadIdx.x;     // 128*512
    int row = idx >> 9;
    int col = idx & 511;
    size_t srow = (size_t)row * SEQN;             // root = pos 0
    float v = (col < HIDN) ? __bfloat162float(h[srow * HIDN + col])
                           : c[srow * HIDN + (col - HIDN)];
    x[idx] = v;
}

// ---------------------------------------------------------------------------
// K3: dense layer  out[M=128, N] = act(A[128, K] @ W[K, N] + bias)
// grid (16 rowgroups of 8, N/64 colgroups). Block 256 thr: thread owns
// 2 rows x 1 col. A staged transposed AsT[K][8] -> float2 broadcast reads.
// ---------------------------------------------------------------------------
template <int K, int N, bool RELU>
__global__ __launch_bounds__(256)
void mlp_kernel(const float* __restrict__ A, int lda,
                const float* __restrict__ W,
                const float* __restrict__ bias,
                float* __restrict__ out)
{
    __shared__ __align__(16) float AsT[K][8];
    const int tid = threadIdx.x;
    const int r0  = blockIdx.x * 8;

    for (int idx = tid; idx < 8 * K; idx += 256) {
        int r = idx / K;
        int k = idx - r * K;
        AsT[k][r] = A[(size_t)(r0 + r) * lda + k];
    }
    __syncthreads();

    const int c   = tid & 63;
    const int rp  = (tid >> 6) * 2;
    const int col = blockIdx.y * 64 + c;

    float acc0 = 0.f, acc1 = 0.f;
#pragma unroll 4
    for (int k = 0; k < K; ++k) {
        float2 a2 = *(const float2*)&AsT[k][rp];
        float w = W[(size_t)k * N + col];
        acc0 += a2.x * w;
        acc1 += a2.y * w;
    }
    float bv = bias[col];
    float v0 = acc0 + bv, v1 = acc1 + bv;
    if (RELU) { v0 = fmaxf(v0, 0.f); v1 = fmaxf(v1, 0.f); }
    out[(size_t)(r0 + rp)     * N + col] = v0;
    out[(size_t)(r0 + rp + 1) * N + col] = v1;
}

// ---------------------------------------------------------------------------
// K4: final layer (N=3): one wave per row, lane-parallel K, shuffle reduce.
// grid = 32 blocks x 4 waves.
// ---------------------------------------------------------------------------
__global__ __launch_bounds__(256)
void mlp_out_kernel(const float* __restrict__ A,
                    const float* __restrict__ Wo,
                    const float* __restrict__ bo,
                    float* __restrict__ out)
{
    const int lane = threadIdx.x & 63;
    const int row  = blockIdx.x * 4 + (threadIdx.x >> 6);
    float a0 = 0.f, a1 = 0.f, a2 = 0.f;
    for (int k = lane; k < MLPD; k += 64) {
        float x = A[(size_t)row * MLPD + k];
        a0 += x * Wo[k * NCLS + 0];
        a1 += x * Wo[k * NCLS + 1];
        a2 += x * Wo[k * NCLS + 2];
    }
#pragma unroll
    for (int off = 32; off >= 1; off >>= 1) {
        a0 += __shfl_down(a0, off, 64);
        a1 += __shfl_down(a1, off, 64);
        a2 += __shfl_down(a2, off, 64);
    }
    if (lane == 0) {
        out[row * NCLS + 0] = a0 + bo[0];
        out[row * NCLS + 1] = a1 + bo[1];
        out[row * NCLS + 2] = a2 + bo[2];
    }
}

// ---------------------------------------------------------------------------
extern "C" void kernel_launch(void* const* d_in, const int* in_sizes, int n_in,
                              void* d_out, int out_size, void* d_ws, size_t ws_size,
                              hipStream_t stream)
{
    const int*   sent = (const int*)d_in[0];
    const float* emb  = (const float*)d_in[2];
    const float* Wp   = (const float*)d_in[3];
    const float* bp   = (const float*)d_in[4];
    const float* Wl   = (const float*)d_in[5];
    const float* Wr   = (const float*)d_in[6];
    const float* bc   = (const float*)d_in[7];
    const float* W0   = (const float*)d_in[8];
    const float* b0   = (const float*)d_in[9];
    const float* W1   = (const float*)d_in[10];
    const float* b1   = (const float*)d_in[11];
    const float* Wo   = (const float*)d_in[12];
    const float* bo   = (const float*)d_in[13];
    float* outp = (float*)d_out;

    const size_t NSTATE = (size_t)BATCHN * SEQN * HIDN;

    char* p = (char*)d_ws;
    __hip_bfloat16* h0 = (__hip_bfloat16*)p;  p += NSTATE * 2;
    __hip_bfloat16* h1 = (__hip_bfloat16*)p;  p += NSTATE * 2;
    float* c0 = (float*)p;                    p += NSTATE * 4;
    float* c1 = (float*)p;                    p += NSTATE * 4;
    __hip_bfloat16* Bp = (__hip_bfloat16*)p;  p += (size_t)512 * NGATES * 2;
    float* xr = (float*)p;                    p += (size_t)BATCHN * MDIM * 4;
    float* x0 = (float*)p;                    p += (size_t)BATCHN * MLPD * 4;
    float* x1 = (float*)p;                    p += (size_t)BATCHN * MLPD * 4;

    // 0) pack weights to bf16 fragment layout
    pack_B_kernel<<<(64 * NGATES + 255) / 256, 256, 0, stream>>>(Wl, Wr, Bp);

    // 1) embedding gather + projection
    embed_proj_kernel<<<(BATCHN * SEQN) / 8, 256, 0, stream>>>(sent, emb, Wp, bp, h0, c0);

    // 2) 63 sequential tree-LSTM levels (ping-pong h/c buffers)
    __hip_bfloat16* hc = h0; __hip_bfloat16* hn = h1;
    float* cc = c0; float* cn = c1;
    for (int R = SEQN - 1; R >= 1; --R) {
        dim3 grid(R, 4);
        tree_level_mfma<<<grid, 256, 0, stream>>>(hc, cc, hn, cn, Bp, bc);
        __hip_bfloat16* th = hc; hc = hn; hn = th;
        float* tc = cc; cc = cn; cn = tc;
    }

    // 3) MLP head on root states
    gather_root_kernel<<<(BATCHN * MDIM) / 256, 256, 0, stream>>>(hc, cc, xr);
    mlp_kernel<512,  MLPD, true ><<<dim3(16, 16), 256, 0, stream>>>(xr, MDIM, W0, b0, x0);
    mlp_kernel<MLPD, MLPD, true ><<<dim3(16, 16), 256, 0, stream>>>(x0, MLPD, W1, b1, x1);
    mlp_out_kernel<<<32, 256, 0, stream>>>(x1, Wo, bo, outp);
}

// Round 4
// 1570.866 us; speedup vs baseline: 7.3217x; 1.4267x over previous
//
#include <hip/hip_runtime.h>
#include <hip/hip_bf16.h>
#include <math.h>

#define BATCHN   128
#define SEQN     64
#define WDIM     300
#define WDIMP    320            // padded K for embed GEMM
#define MDIM     512
#define HIDN     256
#define NGATES   1280           // 5*HIDN
#define MLPD     1024
#define NCLS     3

typedef __bf16 bf16x8 __attribute__((ext_vector_type(8)));
typedef float  f32x4  __attribute__((ext_vector_type(4)));

__device__ __forceinline__ float sigmoidf_(float x) {
    return 1.0f / (1.0f + __expf(-x));
}
__device__ __forceinline__ float tanhf_(float x) {
    x = fminf(fmaxf(x, -15.0f), 15.0f);
    float e = __expf(2.0f * x);
    return (e - 1.0f) / (e + 1.0f);
}

// ---------------------------------------------------------------------------
// Pack B = [W_l ; W_r] (512 x 1280 fp32) into bf16 MFMA-fragment order:
// Bp[kc][n][j] with k = kc*8 + j -> lane's 8 k-elems are 16B contiguous.
// ---------------------------------------------------------------------------
__global__ __launch_bounds__(256)
void pack_B_kernel(const float* __restrict__ Wl, const float* __restrict__ Wr,
                   __hip_bfloat16* __restrict__ Bp)
{
    int idx = blockIdx.x * 256 + threadIdx.x;      // over [64][1280] (kc, n)
    if (idx >= 64 * NGATES) return;
    int kc = idx / NGATES;
    int n  = idx - kc * NGATES;
    __hip_bfloat16 tmp[8];
#pragma unroll
    for (int j = 0; j < 8; ++j) {
        int k = kc * 8 + j;
        float v = (k < HIDN) ? Wl[k * NGATES + n] : Wr[(k - HIDN) * NGATES + n];
        tmp[j] = __float2bfloat16(v);
    }
    *(bf16x8*)(Bp + (size_t)idx * 8) = *(const bf16x8*)tmp;
}

// ---------------------------------------------------------------------------
// Generic pack: f32 W[K][N] -> bf16 Bp[KC][N][8], zero-padded past K.
// ---------------------------------------------------------------------------
__global__ __launch_bounds__(256)
void pack_w_kernel(const float* __restrict__ W, __hip_bfloat16* __restrict__ Bp,
                   int K, int N, int KC)
{
    int idx = blockIdx.x * 256 + threadIdx.x;      // over [KC][N]
    if (idx >= KC * N) return;
    int kc = idx / N;
    int n  = idx - kc * N;
    __hip_bfloat16 tmp[8];
#pragma unroll
    for (int j = 0; j < 8; ++j) {
        int k = kc * 8 + j;
        float v = (k < K) ? W[(size_t)k * N + n] : 0.f;
        tmp[j] = __float2bfloat16(v);
    }
    *(bf16x8*)(Bp + (size_t)idx * 8) = *(const bf16x8*)tmp;
}

// ---------------------------------------------------------------------------
// K1: embed gather + projection via MFMA.
// Block = 32 tokens, 4 waves; wave covers 128 output cols (8 colfrags).
// A (emb rows, f32) staged to LDS as bf16 fragments, K padded to 320.
// cols 0..255 -> h (bf16), cols 256..511 -> c (f32).
// ---------------------------------------------------------------------------
__global__ __launch_bounds__(256)
void embed_mfma_kernel(const int* __restrict__ sent,
                       const float* __restrict__ emb,
                       const __hip_bfloat16* __restrict__ BpWp,  // [40][512][8]
                       const float* __restrict__ bp,
                       __hip_bfloat16* __restrict__ hout,
                       float* __restrict__ cout)
{
    __shared__ __align__(16) __hip_bfloat16 Ae[WDIMP / 8][32][8];   // 20 KB
    const int tid  = threadIdx.x;
    const int tok0 = blockIdx.x * 32;

    for (int idx = tid; idx < 32 * WDIMP; idx += 256) {
        int r = idx / WDIMP;
        int k = idx - r * WDIMP;
        float v = (k < WDIM) ? emb[(size_t)sent[tok0 + r] * WDIM + k] : 0.f;
        Ae[k >> 3][r][k & 7] = __float2bfloat16(v);
    }
    __syncthreads();

    const int lane = tid & 63;
    const int wid  = tid >> 6;
    const int l15  = lane & 15;
    const int kgrp = lane >> 4;

    f32x4 acc[2][8];
#pragma unroll
    for (int rf = 0; rf < 2; ++rf)
#pragma unroll
        for (int cf = 0; cf < 8; ++cf)
            acc[rf][cf] = (f32x4){0.f, 0.f, 0.f, 0.f};

    const bf16x8* BpV = (const bf16x8*)BpWp;
#pragma unroll
    for (int kstep = 0; kstep < WDIMP / 32; ++kstep) {
        const int kc = kstep * 4 + kgrp;
        bf16x8 a0 = *(const bf16x8*)&Ae[kc][l15][0];
        bf16x8 a1 = *(const bf16x8*)&Ae[kc][16 + l15][0];
        const bf16x8* Brow = BpV + (size_t)kc * MDIM + wid * 128 + l15;
#pragma unroll
        for (int cf = 0; cf < 8; ++cf) {
            bf16x8 bfr = Brow[cf * 16];
            acc[0][cf] = __builtin_amdgcn_mfma_f32_16x16x32_bf16(a0, bfr, acc[0][cf], 0, 0, 0);
            acc[1][cf] = __builtin_amdgcn_mfma_f32_16x16x32_bf16(a1, bfr, acc[1][cf], 0, 0, 0);
        }
    }

#pragma unroll
    for (int rf = 0; rf < 2; ++rf)
#pragma unroll
        for (int reg = 0; reg < 4; ++reg) {
            int row = tok0 + rf * 16 + kgrp * 4 + reg;
#pragma unroll
            for (int cf = 0; cf < 8; ++cf) {
                int col = wid * 128 + cf * 16 + l15;
                float v = acc[rf][cf][reg] + bp[col];
                if (col < HIDN)
                    hout[(size_t)row * HIDN + col] = __float2bfloat16(v);
                else
                    cout[(size_t)row * HIDN + (col - HIDN)] = v;
            }
        }
}

// ---------------------------------------------------------------------------
// K2: one tree-LSTM level via MFMA. Block = 4 waves = 128 batch rows at tree
// position p = blockIdx.x; slice = blockIdx.y (8 slices of 32 hid cols).
// Wave: 32 rows x 32 cols x 5 gates; acc[2][2][5] f32x4 = 80 VGPR.
// B staged in k-chunks of 64 (double-buffered 40 KB), 5 exact 4KB
// global_load_lds calls per chunk, flat-linear LDS layout.
// ---------------------------------------------------------------------------
__global__ __launch_bounds__(256, 2)
void tree_level_mfma(const __hip_bfloat16* __restrict__ h_in,
                     const float* __restrict__ c_in,
                     __hip_bfloat16* __restrict__ h_out,
                     float* __restrict__ c_out,
                     const __hip_bfloat16* __restrict__ Bp,
                     const float* __restrict__ bc)
{
    __shared__ __align__(16) __hip_bfloat16 Bs[2][8][160][8];   // 40 KB

    const int tid   = threadIdx.x;
    const int lane  = tid & 63;
    const int wid   = tid >> 6;
    const int p     = blockIdx.x;          // tree position (0..R-1)
    const int slice = blockIdx.y;          // hid cols slice*32..+31
    const int l15   = lane & 15;
    const int kgrp  = lane >> 4;
    const int b0    = wid * 32;            // this wave's batch-row base

    f32x4 acc[2][2][5];
#pragma unroll
    for (int rf = 0; rf < 2; ++rf)
#pragma unroll
        for (int cf = 0; cf < 2; ++cf)
#pragma unroll
            for (int g = 0; g < 5; ++g)
                acc[rf][cf][g] = (f32x4){0.f, 0.f, 0.f, 0.f};

    // stage k-chunk ch (64 k) into buffer buf: 5 calls x 256 thr x 16B
#define STAGE_CHUNK(ch, buf)                                                     \
    {                                                                            \
        _Pragma("unroll")                                                        \
        for (int i = 0; i < 5; ++i) {                                            \
            int flat  = i * 256 + tid;            /* 0..1279 */                  \
            int kgrp8 = flat / 160;                                              \
            int rem   = flat - kgrp8 * 160;                                      \
            int g_    = rem >> 5;                                                \
            int cf_   = (rem >> 4) & 1;                                          \
            int l_    = rem & 15;                                                \
            const __hip_bfloat16* src_ = Bp +                                    \
                ((size_t)((ch) * 8 + kgrp8) * NGATES + g_ * HIDN +               \
                 slice * 32 + cf_ * 16 + l_) * 8;                                \
            __builtin_amdgcn_global_load_lds(                                    \
                (const __attribute__((address_space(1))) unsigned int*)src_,     \
                (__attribute__((address_space(3))) unsigned int*)                \
                    (&Bs[buf][0][0][0] + (size_t)(i * 256 + wid * 64) * 8),      \
                16, 0, 0);                                                       \
        }                                                                        \
    }

    STAGE_CHUNK(0, 0);
    __syncthreads();

    for (int ch = 0; ch < 8; ++ch) {
        const int buf = ch & 1;
        if (ch < 7) STAGE_CHUNK(ch + 1, buf ^ 1);

#pragma unroll
        for (int s = 0; s < 2; ++s) {
            const int kg   = ch * 64 + s * 32 + kgrp * 8;
            const int half = kg >> 8;             // 0 = left child, 1 = right
            const int kl   = kg & 255;
            bf16x8 a0 = *(const bf16x8*)(h_in + ((size_t)(b0 + l15)      * SEQN + p + half) * HIDN + kl);
            bf16x8 a1 = *(const bf16x8*)(h_in + ((size_t)(b0 + 16 + l15) * SEQN + p + half) * HIDN + kl);
            const int kr = s * 4 + kgrp;
#pragma unroll
            for (int g = 0; g < 5; ++g)
#pragma unroll
                for (int cf = 0; cf < 2; ++cf) {
                    bf16x8 bfr = *(const bf16x8*)&Bs[buf][kr][g * 32 + cf * 16 + l15][0];
                    acc[0][cf][g] = __builtin_amdgcn_mfma_f32_16x16x32_bf16(a0, bfr, acc[0][cf][g], 0, 0, 0);
                    acc[1][cf][g] = __builtin_amdgcn_mfma_f32_16x16x32_bf16(a1, bfr, acc[1][cf][g], 0, 0, 0);
                }
        }
        __syncthreads();
    }
#undef STAGE_CHUNK

    // ---- epilogue: C/D layout col = lane&15, row = (lane>>4)*4 + reg
    const int colbase = slice * 32 + l15;
    float bias[2][5];
#pragma unroll
    for (int cf = 0; cf < 2; ++cf)
#pragma unroll
        for (int g = 0; g < 5; ++g)
            bias[cf][g] = bc[g * HIDN + colbase + cf * 16];

#pragma unroll
    for (int rf = 0; rf < 2; ++rf)
#pragma unroll
        for (int reg = 0; reg < 4; ++reg) {
            int srow = (b0 + rf * 16 + kgrp * 4 + reg) * SEQN + p;
            const float* cl = c_in + (size_t)srow * HIDN;
            const float* cr = cl + (size_t)HIDN;   // right child = srow + 1
            __hip_bfloat16* ho = h_out + (size_t)srow * HIDN;
            float*          co = c_out + (size_t)srow * HIDN;
#pragma unroll
            for (int cf = 0; cf < 2; ++cf) {
                int col = colbase + cf * 16;
                float i_ = acc[rf][cf][0][reg] + bias[cf][0];
                float fl = acc[rf][cf][1][reg] + bias[cf][1];
                float fr = acc[rf][cf][2][reg] + bias[cf][2];
                float o_ = acc[rf][cf][3][reg] + bias[cf][3];
                float g_ = acc[rf][cf][4][reg] + bias[cf][4];
                float c  = cl[col] * sigmoidf_(fl) + cr[col] * sigmoidf_(fr)
                         + sigmoidf_(i_) * tanhf_(g_);
                ho[col] = __float2bfloat16(sigmoidf_(o_) * tanhf_(c));
                co[col] = c;
            }
        }
}

// ---------------------------------------------------------------------------
// Assemble MLP input (bf16): x[b,:] = [ h(root_b) | bf16(c(root_b)) ]
// ---------------------------------------------------------------------------
__global__ __launch_bounds__(256)
void gather_root_kernel(const __hip_bfloat16* __restrict__ h,
                        const float* __restrict__ c,
                        __hip_bfloat16* __restrict__ x)
{
    int idx = blockIdx.x * 256 + threadIdx.x;     // 128*512
    int row = idx >> 9;
    int col = idx & 511;
    size_t srow = (size_t)row * SEQN;             // root = pos 0
    __hip_bfloat16 v = (col < HIDN) ? h[srow * HIDN + col]
                                    : __float2bfloat16(c[srow * HIDN + (col - HIDN)]);
    x[idx] = v;
}

// ---------------------------------------------------------------------------
// K3: MFMA dense layer  out[128, N] = relu(A[128, K] @ W + bias), bf16 I/O.
// 1-wave blocks: 32 rows x 64 cols; grid (4, N/64). B direct from packed
// global (read once), no LDS, no barriers -> compiler pipelines freely.
// ---------------------------------------------------------------------------
template <int K, int N, bool RELU>
__global__ __launch_bounds__(64)
void mlp_mfma_kernel(const __hip_bfloat16* __restrict__ A,
                     const __hip_bfloat16* __restrict__ Bp,
                     const float* __restrict__ bias,
                     __hip_bfloat16* __restrict__ out)
{
    const int lane = threadIdx.x;
    const int l15  = lane & 15;
    const int kgrp = lane >> 4;
    const int m0   = blockIdx.x * 32;
    const int col0 = blockIdx.y * 64;

    f32x4 acc[2][4];
#pragma unroll
    for (int rf = 0; rf < 2; ++rf)
#pragma unroll
        for (int cf = 0; cf < 4; ++cf)
            acc[rf][cf] = (f32x4){0.f, 0.f, 0.f, 0.f};

    const bf16x8* BpV = (const bf16x8*)Bp;
#pragma unroll 4
    for (int kstep = 0; kstep < K / 32; ++kstep) {
        const int kl = kstep * 32 + kgrp * 8;
        bf16x8 a0 = *(const bf16x8*)(A + (size_t)(m0 + l15)      * K + kl);
        bf16x8 a1 = *(const bf16x8*)(A + (size_t)(m0 + 16 + l15) * K + kl);
        const bf16x8* Brow = BpV + (size_t)(kstep * 4 + kgrp) * N + col0 + l15;
#pragma unroll
        for (int cf = 0; cf < 4; ++cf) {
            bf16x8 bfr = Brow[cf * 16];
            acc[0][cf] = __builtin_amdgcn_mfma_f32_16x16x32_bf16(a0, bfr, acc[0][cf], 0, 0, 0);
            acc[1][cf] = __builtin_amdgcn_mfma_f32_16x16x32_bf16(a1, bfr, acc[1][cf], 0, 0, 0);
        }
    }

#pragma unroll
    for (int rf = 0; rf < 2; ++rf)
#pragma unroll
        for (int reg = 0; reg < 4; ++reg) {
            int m = m0 + rf * 16 + kgrp * 4 + reg;
#pragma unroll
            for (int cf = 0; cf < 4; ++cf) {
                int col = col0 + cf * 16 + l15;
                float v = acc[rf][cf][reg] + bias[col];
                if (RELU) v = fmaxf(v, 0.f);
                out[(size_t)m * N + col] = __float2bfloat16(v);
            }
        }
}

// ---------------------------------------------------------------------------
// K4: final layer (N=3): one wave per row, lane-parallel K, shuffle reduce.
// ---------------------------------------------------------------------------
__global__ __launch_bounds__(256)
void mlp_out_kernel(const __hip_bfloat16* __restrict__ A,
                    const float* __restrict__ Wo,
                    const float* __restrict__ bo,
                    float* __restrict__ out)
{
    const int lane = threadIdx.x & 63;
    const int row  = blockIdx.x * 4 + (threadIdx.x >> 6);
    float a0 = 0.f, a1 = 0.f, a2 = 0.f;
    for (int k = lane; k < MLPD; k += 64) {
        float x = __bfloat162float(A[(size_t)row * MLPD + k]);
        a0 += x * Wo[k * NCLS + 0];
        a1 += x * Wo[k * NCLS + 1];
        a2 += x * Wo[k * NCLS + 2];
    }
#pragma unroll
    for (int off = 32; off >= 1; off >>= 1) {
        a0 += __shfl_down(a0, off, 64);
        a1 += __shfl_down(a1, off, 64);
        a2 += __shfl_down(a2, off, 64);
    }
    if (lane == 0) {
        out[row * NCLS + 0] = a0 + bo[0];
        out[row * NCLS + 1] = a1 + bo[1];
        out[row * NCLS + 2] = a2 + bo[2];
    }
}

// ---------------------------------------------------------------------------
extern "C" void kernel_launch(void* const* d_in, const int* in_sizes, int n_in,
                              void* d_out, int out_size, void* d_ws, size_t ws_size,
                              hipStream_t stream)
{
    const int*   sent = (const int*)d_in[0];
    const float* emb  = (const float*)d_in[2];
    const float* Wp   = (const float*)d_in[3];
    const float* bp   = (const float*)d_in[4];
    const float* Wl   = (const float*)d_in[5];
    const float* Wr   = (const float*)d_in[6];
    const float* bc   = (const float*)d_in[7];
    const float* W0   = (const float*)d_in[8];
    const float* b0   = (const float*)d_in[9];
    const float* W1   = (const float*)d_in[10];
    const float* b1   = (const float*)d_in[11];
    const float* Wo   = (const float*)d_in[12];
    const float* bo   = (const float*)d_in[13];
    float* outp = (float*)d_out;

    const size_t NSTATE = (size_t)BATCHN * SEQN * HIDN;

    char* p = (char*)d_ws;
    __hip_bfloat16* h0   = (__hip_bfloat16*)p;  p += NSTATE * 2;
    __hip_bfloat16* h1   = (__hip_bfloat16*)p;  p += NSTATE * 2;
    float* c0            = (float*)p;           p += NSTATE * 4;
    float* c1            = (float*)p;           p += NSTATE * 4;
    __hip_bfloat16* Bp   = (__hip_bfloat16*)p;  p += (size_t)512 * NGATES * 2;
    __hip_bfloat16* BpWp = (__hip_bfloat16*)p;  p += (size_t)WDIMP * MDIM * 2;
    __hip_bfloat16* BpW0 = (__hip_bfloat16*)p;  p += (size_t)MDIM * MLPD * 2;
    __hip_bfloat16* BpW1 = (__hip_bfloat16*)p;  p += (size_t)MLPD * MLPD * 2;
    __hip_bfloat16* xr   = (__hip_bfloat16*)p;  p += (size_t)BATCHN * MDIM * 2;
    __hip_bfloat16* x0   = (__hip_bfloat16*)p;  p += (size_t)BATCHN * MLPD * 2;
    __hip_bfloat16* x1   = (__hip_bfloat16*)p;  p += (size_t)BATCHN * MLPD * 2;

    // 0) weight packs (bf16 fragment layout)
    pack_B_kernel<<<(64 * NGATES + 255) / 256, 256, 0, stream>>>(Wl, Wr, Bp);
    pack_w_kernel<<<((WDIMP / 8) * MDIM + 255) / 256, 256, 0, stream>>>(Wp, BpWp, WDIM, MDIM, WDIMP / 8);
    pack_w_kernel<<<((MDIM / 8) * MLPD + 255) / 256, 256, 0, stream>>>(W0, BpW0, MDIM, MLPD, MDIM / 8);
    pack_w_kernel<<<((MLPD / 8) * MLPD + 255) / 256, 256, 0, stream>>>(W1, BpW1, MLPD, MLPD, MLPD / 8);

    // 1) embedding gather + projection (MFMA)
    embed_mfma_kernel<<<(BATCHN * SEQN) / 32, 256, 0, stream>>>(sent, emb, BpWp, bp, h0, c0);

    // 2) 63 sequential tree-LSTM levels (ping-pong h/c buffers)
    __hip_bfloat16* hc = h0; __hip_bfloat16* hn = h1;
    float* cc = c0; float* cn = c1;
    for (int R = SEQN - 1; R >= 1; --R) {
        dim3 grid(R, 8);
        tree_level_mfma<<<grid, 256, 0, stream>>>(hc, cc, hn, cn, Bp, bc);
        __hip_bfloat16* th = hc; hc = hn; hn = th;
        float* tc = cc; cc = cn; cn = tc;
    }

    // 3) MLP head on root states (bf16 MFMA)
    gather_root_kernel<<<(BATCHN * MDIM) / 256, 256, 0, stream>>>(hc, cc, xr);
    mlp_mfma_kernel<MDIM, MLPD, true><<<dim3(4, 16), 64, 0, stream>>>(xr, BpW0, b0, x0);
    mlp_mfma_kernel<MLPD, MLPD, true><<<dim3(4, 16), 64, 0, stream>>>(x0, BpW1, b1, x1);
    mlp_out_kernel<<<32, 256, 0, stream>>>(x1, Wo, bo, outp);
}

// Round 5
// 1472.874 us; speedup vs baseline: 7.8088x; 1.0665x over previous
//
#include <hip/hip_runtime.h>
#include <hip/hip_bf16.h>
#include <math.h>

#define BATCHN   128
#define SEQN     64
#define WDIM     300
#define WDIMP    320            // padded K for embed GEMM
#define MDIM     512
#define HIDN     256
#define NGATES   1280           // 5*HIDN
#define MLPD     1024
#define NCLS     3

typedef __bf16 bf16x8 __attribute__((ext_vector_type(8)));
typedef float  f32x4  __attribute__((ext_vector_type(4)));

__device__ __forceinline__ float sigmoidf_(float x) {
    return 1.0f / (1.0f + __expf(-x));
}
__device__ __forceinline__ float tanhf_(float x) {
    x = fminf(fmaxf(x, -15.0f), 15.0f);
    float e = __expf(2.0f * x);
    return (e - 1.0f) / (e + 1.0f);
}

// ---------------------------------------------------------------------------
// Fused weight pack: all f32 weights -> bf16 MFMA fragment order Bp[kc][n][8]
// seg0: [Wl;Wr] (512x1280)  seg1: Wp (300->320 x 512)
// seg2: W0 (512x1024)       seg3: W1 (1024x1024)
// ---------------------------------------------------------------------------
#define PK_B0   81920           // 64*1280
#define PK_B1   20480           // 40*512
#define PK_B2   65536           // 64*1024
#define PK_B3  131072           // 128*1024
__global__ __launch_bounds__(256)
void pack_all_kernel(const float* __restrict__ Wl, const float* __restrict__ Wr,
                     const float* __restrict__ Wp, const float* __restrict__ W0,
                     const float* __restrict__ W1,
                     __hip_bfloat16* __restrict__ Bp,
                     __hip_bfloat16* __restrict__ BpWp,
                     __hip_bfloat16* __restrict__ BpW0,
                     __hip_bfloat16* __restrict__ BpW1)
{
    int gid = blockIdx.x * 256 + threadIdx.x;
    __hip_bfloat16 tmp[8];
    if (gid < PK_B0) {
        int kc = gid / NGATES, n = gid - kc * NGATES;
#pragma unroll
        for (int j = 0; j < 8; ++j) {
            int k = kc * 8 + j;
            float v = (k < HIDN) ? Wl[k * NGATES + n] : Wr[(k - HIDN) * NGATES + n];
            tmp[j] = __float2bfloat16(v);
        }
        *(bf16x8*)(Bp + (size_t)gid * 8) = *(const bf16x8*)tmp;
    } else if (gid < PK_B0 + PK_B1) {
        int u = gid - PK_B0;
        int kc = u >> 9, n = u & 511;
#pragma unroll
        for (int j = 0; j < 8; ++j) {
            int k = kc * 8 + j;
            tmp[j] = __float2bfloat16((k < WDIM) ? Wp[(size_t)k * MDIM + n] : 0.f);
        }
        *(bf16x8*)(BpWp + (size_t)u * 8) = *(const bf16x8*)tmp;
    } else if (gid < PK_B0 + PK_B1 + PK_B2) {
        int u = gid - PK_B0 - PK_B1;
        int kc = u >> 10, n = u & 1023;
#pragma unroll
        for (int j = 0; j < 8; ++j)
            tmp[j] = __float2bfloat16(W0[(size_t)(kc * 8 + j) * MLPD + n]);
        *(bf16x8*)(BpW0 + (size_t)u * 8) = *(const bf16x8*)tmp;
    } else if (gid < PK_B0 + PK_B1 + PK_B2 + PK_B3) {
        int u = gid - PK_B0 - PK_B1 - PK_B2;
        int kc = u >> 10, n = u & 1023;
#pragma unroll
        for (int j = 0; j < 8; ++j)
            tmp[j] = __float2bfloat16(W1[(size_t)(kc * 8 + j) * MLPD + n]);
        *(bf16x8*)(BpW1 + (size_t)u * 8) = *(const bf16x8*)tmp;
    }
}

// ---------------------------------------------------------------------------
// K1: embed gather + projection via MFMA. Block = 32 tokens x 256 cols,
// grid (256, 2) -> 512 blocks (2/CU). Stage emb rows as bf16 frags (float2
// vectorized), 1 barrier, then 10 k-steps. cols<256 -> h, else -> c.
// ---------------------------------------------------------------------------
__global__ __launch_bounds__(256)
void embed_mfma_kernel(const int* __restrict__ sent,
                       const float* __restrict__ emb,
                       const __hip_bfloat16* __restrict__ BpWp,  // [40][512][8]
                       const float* __restrict__ bp,
                       __hip_bfloat16* __restrict__ hout,
                       float* __restrict__ cout)
{
    __shared__ __align__(16) __hip_bfloat16 Ae[WDIMP / 8][32][8];   // 20 KB
    const int tid  = threadIdx.x;
    const int tok0 = blockIdx.x * 32;

#pragma unroll
    for (int i = 0; i < 20; ++i) {
        int idx = i * 256 + tid;              // over 32 rows x 160 k-pairs
        int r  = idx / 160;
        int kp = idx - r * 160;
        int k  = kp * 2;
        float2 v = make_float2(0.f, 0.f);
        if (k < WDIM)
            v = *(const float2*)&emb[(size_t)sent[tok0 + r] * WDIM + k];
        __hip_bfloat162 h2;
        h2.x = __float2bfloat16(v.x);
        h2.y = __float2bfloat16(v.y);
        *(__hip_bfloat162*)&Ae[k >> 3][r][k & 7] = h2;
    }
    __syncthreads();

    const int lane = tid & 63;
    const int wid  = tid >> 6;
    const int l15  = lane & 15;
    const int kgrp = lane >> 4;
    const int col0 = blockIdx.y * 256 + wid * 64;

    f32x4 acc[2][4];
#pragma unroll
    for (int rf = 0; rf < 2; ++rf)
#pragma unroll
        for (int cf = 0; cf < 4; ++cf)
            acc[rf][cf] = (f32x4){0.f, 0.f, 0.f, 0.f};

    const bf16x8* BpV = (const bf16x8*)BpWp;
#pragma unroll
    for (int ks = 0; ks < WDIMP / 32; ++ks) {
        const int kc = ks * 4 + kgrp;
        bf16x8 a0 = *(const bf16x8*)&Ae[kc][l15][0];
        bf16x8 a1 = *(const bf16x8*)&Ae[kc][16 + l15][0];
        const bf16x8* Brow = BpV + (size_t)kc * MDIM + col0 + l15;
#pragma unroll
        for (int cf = 0; cf < 4; ++cf) {
            bf16x8 bfr = Brow[cf * 16];
            acc[0][cf] = __builtin_amdgcn_mfma_f32_16x16x32_bf16(a0, bfr, acc[0][cf], 0, 0, 0);
            acc[1][cf] = __builtin_amdgcn_mfma_f32_16x16x32_bf16(a1, bfr, acc[1][cf], 0, 0, 0);
        }
    }

#pragma unroll
    for (int rf = 0; rf < 2; ++rf)
#pragma unroll
        for (int reg = 0; reg < 4; ++reg) {
            int row = tok0 + rf * 16 + kgrp * 4 + reg;
#pragma unroll
            for (int cf = 0; cf < 4; ++cf) {
                int col = col0 + cf * 16 + l15;
                float v = acc[rf][cf][reg] + bp[col];
                if (col < HIDN)
                    hout[(size_t)row * HIDN + col] = __float2bfloat16(v);
                else
                    cout[(size_t)row * HIDN + (col - HIDN)] = v;
            }
        }
}

// ---------------------------------------------------------------------------
// K2: one tree-LSTM level via MFMA, B-slice staged ONCE (80 KB LDS, 1
// barrier, no main-loop syncs). Block = 256 rows = 2 tree positions x 128
// batch; wave w -> position 2x+(w>>1), batch half (w&1). Wave tile:
// 64 rows x 16 cols x 5 gates (4 rowfrags share each B frag -> 4:1
// MFMA:ds_read). grid (ceil(R/2), 16 slices) -> 2 blocks/CU at 80 KB.
// ---------------------------------------------------------------------------
__global__ __launch_bounds__(256, 2)
void tree_level_mfma(const __hip_bfloat16* __restrict__ h_in,
                     const float* __restrict__ c_in,
                     __hip_bfloat16* __restrict__ h_out,
                     float* __restrict__ c_out,
                     const __hip_bfloat16* __restrict__ Bp,
                     const float* __restrict__ bc, int R)
{
    __shared__ __align__(16) __hip_bfloat16 Bs[64][5][16][8];   // 80 KB

    const int tid   = threadIdx.x;
    const int lane  = tid & 63;
    const int wid   = tid >> 6;
    const int slice = blockIdx.y;              // hid cols slice*16..+15
    const int l15   = lane & 15;
    const int kgrp  = lane >> 4;

    const int p     = blockIdx.x * 2 + (wid >> 1);
    const bool valid = (p < R);
    const int pl    = valid ? p : 0;           // clamped load position
    const int bbase = (wid & 1) * 64;          // batch-row base for this wave

    // ---- stage B-slice: 20 x (256 thr x 16 B) = 80 KB, linear LDS dest
#pragma unroll
    for (int i = 0; i < 20; ++i) {
        int flat = i * 256 + tid;              // 0..5119 = (kc*5+g)*16 + j
        int kc  = flat / 80;
        int rem = flat - kc * 80;
        int g   = rem >> 4;
        int j   = rem & 15;
        const __hip_bfloat16* src =
            Bp + ((size_t)kc * NGATES + g * HIDN + slice * 16 + j) * 8;
        __builtin_amdgcn_global_load_lds(
            (const __attribute__((address_space(1))) unsigned int*)src,
            (__attribute__((address_space(3))) unsigned int*)
                ((char*)&Bs[0][0][0][0] + (size_t)flat * 16),
            16, 0, 0);
    }
    __syncthreads();

    // A-row bases (per rowfrag, fixed over k): row = bbase + rf*16 + l15
    const __hip_bfloat16* abase[4];
#pragma unroll
    for (int rf = 0; rf < 4; ++rf)
        abase[rf] = h_in + (size_t)((bbase + rf * 16 + l15) * SEQN + pl) * HIDN;

    f32x4 acc[4][5];
#pragma unroll
    for (int rf = 0; rf < 4; ++rf)
#pragma unroll
        for (int g = 0; g < 5; ++g)
            acc[rf][g] = (f32x4){0.f, 0.f, 0.f, 0.f};

#pragma unroll
    for (int ks = 0; ks < 16; ++ks) {
        const int kg = ks * 32 + kgrp * 8;     // 0..511; left rows then right
        bf16x8 a[4];
#pragma unroll
        for (int rf = 0; rf < 4; ++rf)
            a[rf] = *(const bf16x8*)(abase[rf] + kg);
#pragma unroll
        for (int g = 0; g < 5; ++g) {
            bf16x8 bfr = *(const bf16x8*)&Bs[ks * 4 + kgrp][g][l15][0];
#pragma unroll
            for (int rf = 0; rf < 4; ++rf)
                acc[rf][g] = __builtin_amdgcn_mfma_f32_16x16x32_bf16(a[rf], bfr, acc[rf][g], 0, 0, 0);
        }
    }

    // ---- epilogue: C/D layout col = lane&15, row = (lane>>4)*4 + reg
    if (!valid) return;
    const int col = slice * 16 + l15;
    float bias[5];
#pragma unroll
    for (int g = 0; g < 5; ++g) bias[g] = bc[g * HIDN + col];

#pragma unroll
    for (int rf = 0; rf < 4; ++rf)
#pragma unroll
        for (int reg = 0; reg < 4; ++reg) {
            int b = bbase + rf * 16 + kgrp * 4 + reg;
            int srow = b * SEQN + p;
            float clv = c_in[(size_t)srow * HIDN + col];
            float crv = c_in[(size_t)(srow + 1) * HIDN + col];
            float i_ = acc[rf][0][reg] + bias[0];
            float fl = acc[rf][1][reg] + bias[1];
            float fr = acc[rf][2][reg] + bias[2];
            float o_ = acc[rf][3][reg] + bias[3];
            float g_ = acc[rf][4][reg] + bias[4];
            float c  = clv * sigmoidf_(fl) + crv * sigmoidf_(fr)
                     + sigmoidf_(i_) * tanhf_(g_);
            h_out[(size_t)srow * HIDN + col] = __float2bfloat16(sigmoidf_(o_) * tanhf_(c));
            c_out[(size_t)srow * HIDN + col] = c;
        }
}

// ---------------------------------------------------------------------------
// Assemble MLP input (bf16): x[b,:] = [ h(root_b) | bf16(c(root_b)) ]
// ---------------------------------------------------------------------------
__global__ __launch_bounds__(256)
void gather_root_kernel(const __hip_bfloat16* __restrict__ h,
                        const float* __restrict__ c,
                        __hip_bfloat16* __restrict__ x)
{
    int idx = blockIdx.x * 256 + threadIdx.x;     // 128*512
    int row = idx >> 9;
    int col = idx & 511;
    size_t srow = (size_t)row * SEQN;             // root = pos 0
    __hip_bfloat16 v = (col < HIDN) ? h[srow * HIDN + col]
                                    : __float2bfloat16(c[srow * HIDN + (col - HIDN)]);
    x[idx] = v;
}

// ---------------------------------------------------------------------------
// K3: MFMA dense layer  out[128, N] = relu(A[128, K] @ W + bias), bf16 I/O.
// Block 256 thr = 4 waves, wave owns 16 cols; grid (4, N/64) -> 256 waves.
// B direct from packed global (L2-resident), no LDS, no barriers.
// ---------------------------------------------------------------------------
template <int K, int N, bool RELU>
__global__ __launch_bounds__(256)
void mlp_mfma_kernel(const __hip_bfloat16* __restrict__ A,
                     const __hip_bfloat16* __restrict__ Bp,
                     const float* __restrict__ bias,
                     __hip_bfloat16* __restrict__ out)
{
    const int lane = threadIdx.x & 63;
    const int wid  = threadIdx.x >> 6;
    const int l15  = lane & 15;
    const int kgrp = lane >> 4;
    const int m0   = blockIdx.x * 32;
    const int col0 = blockIdx.y * 64 + wid * 16;

    f32x4 acc[2];
    acc[0] = (f32x4){0.f, 0.f, 0.f, 0.f};
    acc[1] = (f32x4){0.f, 0.f, 0.f, 0.f};

    const bf16x8* BpV = (const bf16x8*)Bp;
#pragma unroll 4
    for (int ks = 0; ks < K / 32; ++ks) {
        const int kl = ks * 32 + kgrp * 8;
        bf16x8 a0 = *(const bf16x8*)(A + (size_t)(m0 + l15)      * K + kl);
        bf16x8 a1 = *(const bf16x8*)(A + (size_t)(m0 + 16 + l15) * K + kl);
        bf16x8 bfr = BpV[(size_t)(ks * 4 + kgrp) * N + col0 + l15];
        acc[0] = __builtin_amdgcn_mfma_f32_16x16x32_bf16(a0, bfr, acc[0], 0, 0, 0);
        acc[1] = __builtin_amdgcn_mfma_f32_16x16x32_bf16(a1, bfr, acc[1], 0, 0, 0);
    }

    const int col = col0 + l15;
    const float bv = bias[col];
#pragma unroll
    for (int rf = 0; rf < 2; ++rf)
#pragma unroll
        for (int reg = 0; reg < 4; ++reg) {
            int m = m0 + rf * 16 + kgrp * 4 + reg;
            float v = acc[rf][reg] + bv;
            if (RELU) v = fmaxf(v, 0.f);
            out[(size_t)m * N + col] = __float2bfloat16(v);
        }
}

// ---------------------------------------------------------------------------
// K4: final layer (N=3): one wave per row, lane-parallel K, shuffle reduce.
// ---------------------------------------------------------------------------
__global__ __launch_bounds__(256)
void mlp_out_kernel(const __hip_bfloat16* __restrict__ A,
                    const float* __restrict__ Wo,
                    const float* __restrict__ bo,
                    float* __restrict__ out)
{
    const int lane = threadIdx.x & 63;
    const int row  = blockIdx.x * 4 + (threadIdx.x >> 6);
    float a0 = 0.f, a1 = 0.f, a2 = 0.f;
    for (int k = lane; k < MLPD; k += 64) {
        float x = __bfloat162float(A[(size_t)row * MLPD + k]);
        a0 += x * Wo[k * NCLS + 0];
        a1 += x * Wo[k * NCLS + 1];
        a2 += x * Wo[k * NCLS + 2];
    }
#pragma unroll
    for (int off = 32; off >= 1; off >>= 1) {
        a0 += __shfl_down(a0, off, 64);
        a1 += __shfl_down(a1, off, 64);
        a2 += __shfl_down(a2, off, 64);
    }
    if (lane == 0) {
        out[row * NCLS + 0] = a0 + bo[0];
        out[row * NCLS + 1] = a1 + bo[1];
        out[row * NCLS + 2] = a2 + bo[2];
    }
}

// ---------------------------------------------------------------------------
extern "C" void kernel_launch(void* const* d_in, const int* in_sizes, int n_in,
                              void* d_out, int out_size, void* d_ws, size_t ws_size,
                              hipStream_t stream)
{
    const int*   sent = (const int*)d_in[0];
    const float* emb  = (const float*)d_in[2];
    const float* Wp   = (const float*)d_in[3];
    const float* bp   = (const float*)d_in[4];
    const float* Wl   = (const float*)d_in[5];
    const float* Wr   = (const float*)d_in[6];
    const float* bc   = (const float*)d_in[7];
    const float* W0   = (const float*)d_in[8];
    const float* b0   = (const float*)d_in[9];
    const float* W1   = (const float*)d_in[10];
    const float* b1   = (const float*)d_in[11];
    const float* Wo   = (const float*)d_in[12];
    const float* bo   = (const float*)d_in[13];
    float* outp = (float*)d_out;

    const size_t NSTATE = (size_t)BATCHN * SEQN * HIDN;

    char* p = (char*)d_ws;
    __hip_bfloat16* h0   = (__hip_bfloat16*)p;  p += NSTATE * 2;
    __hip_bfloat16* h1   = (__hip_bfloat16*)p;  p += NSTATE * 2;
    float* c0            = (float*)p;           p += NSTATE * 4;
    float* c1            = (float*)p;           p += NSTATE * 4;
    __hip_bfloat16* Bp   = (__hip_bfloat16*)p;  p += (size_t)512 * NGATES * 2;
    __hip_bfloat16* BpWp = (__hip_bfloat16*)p;  p += (size_t)WDIMP * MDIM * 2;
    __hip_bfloat16* BpW0 = (__hip_bfloat16*)p;  p += (size_t)MDIM * MLPD * 2;
    __hip_bfloat16* BpW1 = (__hip_bfloat16*)p;  p += (size_t)MLPD * MLPD * 2;
    __hip_bfloat16* xr   = (__hip_bfloat16*)p;  p += (size_t)BATCHN * MDIM * 2;
    __hip_bfloat16* x0   = (__hip_bfloat16*)p;  p += (size_t)BATCHN * MLPD * 2;
    __hip_bfloat16* x1   = (__hip_bfloat16*)p;  p += (size_t)BATCHN * MLPD * 2;

    // 0) fused weight pack (bf16 fragment layout)
    const int PK_TOT = PK_B0 + PK_B1 + PK_B2 + PK_B3;
    pack_all_kernel<<<(PK_TOT + 255) / 256, 256, 0, stream>>>(
        Wl, Wr, Wp, W0, W1, Bp, BpWp, BpW0, BpW1);

    // 1) embedding gather + projection (MFMA)
    embed_mfma_kernel<<<dim3(BATCHN * SEQN / 32, 2), 256, 0, stream>>>(
        sent, emb, BpWp, bp, h0, c0);

    // 2) 63 sequential tree-LSTM levels (ping-pong h/c buffers)
    __hip_bfloat16* hc = h0; __hip_bfloat16* hn = h1;
    float* cc = c0; float* cn = c1;
    for (int R = SEQN - 1; R >= 1; --R) {
        dim3 grid((R + 1) / 2, 16);
        tree_level_mfma<<<grid, 256, 0, stream>>>(hc, cc, hn, cn, Bp, bc, R);
        __hip_bfloat16* th = hc; hc = hn; hn = th;
        float* tc = cc; cc = cn; cn = tc;
    }

    // 3) MLP head on root states (bf16 MFMA)
    gather_root_kernel<<<(BATCHN * MDIM) / 256, 256, 0, stream>>>(hc, cc, xr);
    mlp_mfma_kernel<MDIM, MLPD, true><<<dim3(4, 16), 256, 0, stream>>>(xr, BpW0, b0, x0);
    mlp_mfma_kernel<MLPD, MLPD, true><<<dim3(4, 16), 256, 0, stream>>>(x0, BpW1, b1, x1);
    mlp_out_kernel<<<32, 256, 0, stream>>>(x1, Wo, bo, outp);
}